// Round 15
// baseline (526.916 us; speedup 1.0000x reference)
//
#include <hip/hip_runtime.h>

// Problem dims (fixed)
constexpr int Bb = 2, Nn = 8192;
constexpr float SCALE = 0.17677669529663687f;  // 32^-0.5

typedef __attribute__((ext_vector_type(8))) short bf16x8;
typedef __attribute__((ext_vector_type(4))) float f32x4;

__device__ inline unsigned short f2bf(float f) {
  unsigned u = __float_as_uint(f);
  u = (u + 0x7fffu + ((u >> 16) & 1u)) >> 16;
  return (unsigned short)u;
}
__device__ inline float bf2f(short h) {
  return __uint_as_float(((unsigned)(unsigned short)h) << 16);
}
__device__ inline void wait_lds() {
  asm volatile("s_waitcnt lgkmcnt(0)" ::: "memory");
}

// ---------------- prep: (W .* g) fp32 -> bf16 MFMA-B-fragment layout ----------------
__global__ void prep_weights(const float* __restrict__ Wq, const float* __restrict__ Wk,
                             const float* __restrict__ Wv, const float* __restrict__ Wo,
                             const float* __restrict__ gq, const float* __restrict__ gk,
                             const float* __restrict__ gv, short* __restrict__ wsb) {
  int idx = blockIdx.x * 256 + threadIdx.x;   // 0..65535
  int j = idx & 7;
  int lane = (idx >> 3) & 63;
  int ks = (idx >> 9) & 7;
  int nt = idx >> 12;
  int co = nt * 16 + (lane & 15);
  int ci = ks * 32 + (lane >> 4) * 8 + j;
  int src = co * 256 + ci;
  wsb[idx]          = (short)f2bf(Wq[src] * gq[ci]);
  wsb[65536 + idx]  = (short)f2bf(Wk[src] * gk[ci]);
  wsb[131072 + idx] = (short)f2bf(Wv[src] * gv[ci]);
  wsb[196608 + idx] = (short)f2bf(Wo[src]);
}

// LN-fold vectors: u[o] = sum_c W[o][c]*g[c]; t[o] = sum_c W[o][c]*b[c] + bias[o]
__global__ void prep_ut(const float* __restrict__ Wq, const float* __restrict__ Wk,
                        const float* __restrict__ Wv,
                        const float* __restrict__ gq, const float* __restrict__ bq_ln,
                        const float* __restrict__ bq,
                        const float* __restrict__ gk, const float* __restrict__ bk_ln,
                        const float* __restrict__ bk,
                        const float* __restrict__ gv, const float* __restrict__ bv_ln,
                        const float* __restrict__ bv, float* __restrict__ utf) {
  const float *W, *g, *bl, *bias;
  float* dst;
  if (blockIdx.x == 0)      { W = Wq; g = gq; bl = bq_ln; bias = bq; dst = utf; }
  else if (blockIdx.x == 1) { W = Wk; g = gk; bl = bk_ln; bias = bk; dst = utf + 512; }
  else                      { W = Wv; g = gv; bl = bv_ln; bias = bv; dst = utf + 1024; }
  int o = blockIdx.y * 16 + (threadIdx.x >> 4);
  int cl = threadIdx.x & 15;
  float au = 0.f, at = 0.f;
#pragma unroll
  for (int j = 0; j < 4; ++j) {
    float4 w4 = *(const float4*)(W + o * 256 + cl * 16 + j * 4);
    float4 g4 = *(const float4*)(g + cl * 16 + j * 4);
    float4 b4 = *(const float4*)(bl + cl * 16 + j * 4);
    au = fmaf(w4.x, g4.x, fmaf(w4.y, g4.y, fmaf(w4.z, g4.z, fmaf(w4.w, g4.w, au))));
    at = fmaf(w4.x, b4.x, fmaf(w4.y, b4.y, fmaf(w4.z, b4.z, fmaf(w4.w, b4.w, at))));
  }
#pragma unroll
  for (int m = 1; m <= 8; m <<= 1) {
    au += __shfl_xor(au, m, 64);
    at += __shfl_xor(at, m, 64);
  }
  if (cl == 0) {
    dst[o] = au;
    dst[256 + o] = at + bias[o];
  }
}

// Cast a raw fp32 row to bf16 into the swizzled tile. Rows fully independent.
__device__ inline void store_row(const float4 v, int row, char* S, int lane) {
  ushort4 o;
  o.x = f2bf(v.x); o.y = f2bf(v.y); o.z = f2bf(v.z); o.w = f2bf(v.w);
  *(ushort4*)(S + row * 512 + ((lane * 8) ^ ((row & 7) << 4))) = o;
}

// Lane-parallel stats for this wave's 16 just-staged rows: 4 lanes/row from LDS bf16.
__device__ inline void stats16(const char* S, char* ST, int rbase, int lane) {
  wait_lds();   // own ds_writes drained
  int r = rbase + (lane >> 2);
  int q = lane & 3;
  const char* base = S + r * 512;
  int swz = (r & 7) << 4;
  float s = 0.f, ss = 0.f;
#pragma unroll
  for (int j = 0; j < 8; ++j) {
    bf16x8 x = *(const bf16x8*)(base + ((q * 128 + j * 16) ^ swz));
#pragma unroll
    for (int e = 0; e < 8; ++e) {
      float f = bf2f(x[e]);
      s += f;
      ss = fmaf(f, f, ss);
    }
  }
  s  += __shfl_xor(s, 1, 64);  ss += __shfl_xor(ss, 1, 64);
  s  += __shfl_xor(s, 2, 64);  ss += __shfl_xor(ss, 2, 64);
  float mu   = s * (1.0f / 256.0f);
  float var  = ss * (1.0f / 256.0f) - mu * mu;
  float rstd = rsqrtf(var + 1e-5f);
  if (q == 0) {
    float* d = (float*)(ST + r * 8);
    d[0] = rstd;
    d[1] = rstd * mu;
  }
}

// q-row staging keeps the precise in-register shuffle stats (1 row/wave).
__device__ inline void stage_row_q(const float4 v, int row, char* S, float* STrow, int lane) {
  ushort4 o;
  o.x = f2bf(v.x); o.y = f2bf(v.y); o.z = f2bf(v.z); o.w = f2bf(v.w);
  *(ushort4*)(S + row * 512 + ((lane * 8) ^ ((row & 7) << 4))) = o;
  float s  = v.x + v.y + v.z + v.w;
  float ss = fmaf(v.x, v.x, fmaf(v.y, v.y, fmaf(v.z, v.z, v.w * v.w)));
#pragma unroll
  for (int m = 32; m >= 1; m >>= 1) {
    s  += __shfl_xor(s, m, 64);
    ss += __shfl_xor(ss, m, 64);
  }
  float mu   = s * (1.0f / 256.0f);
  float var  = ss * (1.0f / 256.0f) - mu * mu;
  float rstd = rsqrtf(var + 1e-5f);
  if (lane == 0) { STrow[0] = rstd; STrow[1] = rstd * mu; }
}

// 32x256x256 projection, 2-wave col-split (128 cols/wave), two row-passes of 16 rows,
// acc = 32 regs/pass. In-place over S with LN-fold epilogue (R9-proven pattern).
__device__ inline void proj32_ln(char* S, const char* ST, const short* __restrict__ WB,
                                 const float* __restrict__ u, const float* __restrict__ t,
                                 int wave, int lane) {
#pragma unroll
  for (int p = 0; p < 2; ++p) {
    f32x4 acc[8] = {};
#pragma unroll
    for (int ks = 0; ks < 8; ++ks) {
      int row = p * 16 + (lane & 15);
      bf16x8 a = *(const bf16x8*)(S + row * 512 +
                                  ((ks * 64 + (lane >> 4) * 16) ^ ((row & 7) << 4)));
#pragma unroll
      for (int ct = 0; ct < 8; ++ct) {
        bf16x8 bb = *(const bf16x8*)(WB + (((wave * 8 + ct) * 8 + ks) * 64 + lane) * 8);
        acc[ct] = __builtin_amdgcn_mfma_f32_16x16x32_bf16(a, bb, acc[ct], 0, 0, 0);
      }
    }
    __syncthreads();   // both waves done reading staged rows p*16..p*16+15
    float2 st[4];
#pragma unroll
    for (int reg = 0; reg < 4; ++reg) {
      int r = p * 16 + (lane >> 4) * 4 + reg;
      st[reg] = *(const float2*)(ST + r * 8);
    }
#pragma unroll
    for (int ct = 0; ct < 8; ++ct) {
      int c = wave * 128 + ct * 16 + (lane & 15);
      float uc = u[c];
      float tc = t[c];
#pragma unroll
      for (int reg = 0; reg < 4; ++reg) {
        int r = p * 16 + (lane >> 4) * 4 + reg;
        float val = fmaf(st[reg].x, acc[ct][reg], fmaf(-st[reg].y, uc, tc));
        *(unsigned short*)(S + r * 512 + ((c * 2) ^ ((r & 7) << 4))) = f2bf(val);
      }
    }
  }
  __syncthreads();     // full projection visible
}

__global__ __launch_bounds__(128, 2) void geo_attn_main(
    const float* __restrict__ query, const float* __restrict__ key_,
    const float* __restrict__ value, const float* __restrict__ bo,
    const short* __restrict__ wsb, const float* __restrict__ utf,
    float* __restrict__ out) {
  __shared__ char smem[19744];
  char* S   = smem;           // [32][512B] swizzled bf16; rows 0-1 double as q / attn-out A-tile
  char* PR  = smem + 16384;   // [16][16] f32 probs (probs[k][g], g = nl*8+h, nl<2)
  char* QL  = smem + 17408;   // [4][512B] q_proj bf16 (rows 2-3 written, never read)
  char* ST  = smem + 19456;   // [32] float2 row stats (rstd, rstd*mu)
  char* STQ = smem + 19712;   // [2] float2 q row stats (+pad)

  const int tid = threadIdx.x;
  const int lane = tid & 63;
  const int wave = tid >> 6;          // 0..1
  const int blk = blockIdx.x;
  const int b = blk >> 12;            // 4096 blocks per batch
  const int n0 = (blk & 4095) * 2;

  const short* WqB = wsb;
  const short* WkB = wsb + 65536;
  const short* WvB = wsb + 131072;
  const short* WoB = wsb + 196608;
  const float* uq = utf;        const float* tq = utf + 256;
  const float* uk = utf + 512;  const float* tk = utf + 768;
  const float* uv = utf + 1024; const float* tv = utf + 1280;

  const float* ksrc = key_  + (size_t)((b * Nn + n0) * 16) * 256;
  const float* vsrc = value + (size_t)((b * Nn + n0) * 16) * 256;
  const int rbase = wave * 16;        // this wave's 16 staging rows

  // ---- Issue K batch 0 (4 rows); hidden under q-stage + q-proj ----
  float4 kcur[4];
#pragma unroll
  for (int i = 0; i < 4; ++i)
    kcur[i] = *(const float4*)(ksrc + (size_t)(rbase + i) * 256 + lane * 4);

  // ---- Phase 1: q-stage (bf16 + precise stats), one row per wave ----
  {
    float4 v = *(const float4*)(query + (size_t)(b * Nn + n0 + wave) * 256 + lane * 4);
    stage_row_q(v, wave, S, (float*)(STQ + wave * 8), lane);
  }
  __syncthreads();

  // ---- Phase 2: q-proj mini-GEMM (LN-fold epilogue), 128 cols/wave -> QL ----
  {
    f32x4 qacc[8] = {};
#pragma unroll
    for (int ks = 0; ks < 8; ++ks) {
      int arow = lane & 15;
      bf16x8 a = *(const bf16x8*)(S + arow * 512 +
                                  ((ks * 64 + (lane >> 4) * 16) ^ ((arow & 7) << 4)));
#pragma unroll
      for (int ct = 0; ct < 8; ++ct) {
        bf16x8 bb = *(const bf16x8*)(WqB + (((wave * 8 + ct) * 8 + ks) * 64 + lane) * 8);
        qacc[ct] = __builtin_amdgcn_mfma_f32_16x16x32_bf16(a, bb, qacc[ct], 0, 0, 0);
      }
    }
    if ((lane >> 4) == 0) {
#pragma unroll
      for (int ct = 0; ct < 8; ++ct) {
        int c = wave * 128 + ct * 16 + (lane & 15);
        float uc = uq[c];
        float tc = tq[c];
#pragma unroll
        for (int reg = 0; reg < 2; ++reg) {   // rows 0-1 only (TN=2)
          float2 stq = *(const float2*)(STQ + reg * 8);
          float val = fmaf(stq.x, qacc[ct][reg], fmaf(-stq.y, uc, tc));
          *(unsigned short*)(QL + reg * 512 + c * 2) = f2bf(val);
        }
      }
    }
  }
  __syncthreads();   // QL visible; S free for K-stage

  // ---- Phase 3: K-stage (16 rows/wave) + lane-parallel stats ----
  {
#pragma unroll
    for (int i = 0; i < 4; ++i) store_row(kcur[i], rbase + i, S, lane);
#pragma unroll
    for (int i = 4; i < 16; ++i) {
      float4 v = *(const float4*)(ksrc + (size_t)(rbase + i) * 256 + lane * 4);
      store_row(v, rbase + i, S, lane);
    }
    stats16(S, ST, rbase, lane);
  }
  __syncthreads();

  // ---- Phase 4: K-proj with LN-fold (two row-passes, in-place) ----
  proj32_ln(S, ST, WkB, uk, tk, wave, lane);

  // ---- Issue V batch 0: hidden under logits+softmax ----
  float4 vcur[4];
#pragma unroll
  for (int i = 0; i < 4; ++i)
    vcur[i] = *(const float4*)(vsrc + (size_t)(rbase + i) * 256 + lane * 4);

  // ---- Phase 5: logits + fused softmax (8-lane groups) -> PR ----
  {
    int g = tid >> 3;         // 0..15 = nl*8 + h
    int nl = g >> 3, h = g & 7;
    int k0 = (tid & 7) * 2;
    float a0 = 0.f, a1 = 0.f;
#pragma unroll
    for (int kk = 0; kk < 2; ++kk) {
      int row = nl * 16 + k0 + kk;
      float a = 0.f;
#pragma unroll
      for (int j4 = 0; j4 < 4; ++j4) {
        bf16x8 qq = *(const bf16x8*)(QL + nl * 512 + h * 64 + j4 * 16);
        bf16x8 kv = *(const bf16x8*)(S + row * 512 +
                                     ((h * 64 + j4 * 16) ^ ((row & 7) << 4)));
#pragma unroll
        for (int j = 0; j < 8; ++j) a = fmaf(bf2f(qq[j]), bf2f(kv[j]), a);
      }
      if (kk == 0) a0 = a * SCALE; else a1 = a * SCALE;
    }
    float m = fmaxf(a0, a1);
#pragma unroll
    for (int msk = 1; msk <= 4; msk <<= 1) m = fmaxf(m, __shfl_xor(m, msk, 64));
    float e0 = __expf(a0 - m), e1 = __expf(a1 - m);
    float ssum = e0 + e1;
#pragma unroll
    for (int msk = 1; msk <= 4; msk <<= 1) ssum += __shfl_xor(ssum, msk, 64);
    float inv = 1.0f / ssum;
    *(float*)(PR + ((k0)     * 16 + g) * 4) = e0 * inv;
    *(float*)(PR + ((k0 + 1) * 16 + g) * 4) = e1 * inv;
  }
  __syncthreads();   // S (K-proj) reads done; V-stage may overwrite

  // ---- Phase 6: V-stage (16 rows/wave) + lane-parallel stats ----
  {
#pragma unroll
    for (int i = 0; i < 4; ++i) store_row(vcur[i], rbase + i, S, lane);
#pragma unroll
    for (int i = 4; i < 16; ++i) {
      float4 v = *(const float4*)(vsrc + (size_t)(rbase + i) * 256 + lane * 4);
      store_row(v, rbase + i, S, lane);
    }
    stats16(S, ST, rbase, lane);
  }
  __syncthreads();

  // ---- Phase 7: V-proj with LN-fold (two row-passes, in-place) ----
  proj32_ln(S, ST, WvB, uv, tv, wave, lane);

  // ---- Phase 8: PV -> regs ----
  float o0 = 0.f, o1 = 0.f, o2 = 0.f, o3 = 0.f;
  {
    int nl = wave;            // 0..1
    int c0 = lane * 4;
    int h = c0 >> 5;
#pragma unroll
    for (int k = 0; k < 16; ++k) {
      float p = *(const float*)(PR + (k * 16 + nl * 8 + h) * 4);
      int row = nl * 16 + k;
      ushort4 vv = *(const ushort4*)(S + row * 512 + ((c0 * 2) ^ ((row & 7) << 4)));
      o0 = fmaf(p, bf2f((short)vv.x), o0);
      o1 = fmaf(p, bf2f((short)vv.y), o1);
      o2 = fmaf(p, bf2f((short)vv.z), o2);
      o3 = fmaf(p, bf2f((short)vv.w), o3);
    }
  }
  __syncthreads();   // all S reads done before overwrite
  {
    int nl = wave;
    int c0 = lane * 4;
    ushort4 ob;
    ob.x = f2bf(o0); ob.y = f2bf(o1); ob.z = f2bf(o2); ob.w = f2bf(o3);
    *(ushort4*)(S + nl * 512 + ((c0 * 2) ^ ((nl & 7) << 4))) = ob;
  }
  __syncthreads();

  // ---- Phase 9: out-proj GEMM + store (A rows 2-15 garbage -> discarded) ----
  {
    f32x4 oacc[8] = {};
#pragma unroll
    for (int ks = 0; ks < 8; ++ks) {
      int arow = lane & 15;
      bf16x8 a = *(const bf16x8*)(S + arow * 512 +
                                  ((ks * 64 + (lane >> 4) * 16) ^ ((arow & 7) << 4)));
#pragma unroll
      for (int ct = 0; ct < 8; ++ct) {
        bf16x8 bb = *(const bf16x8*)(WoB + (((wave * 8 + ct) * 8 + ks) * 64 + lane) * 8);
        oacc[ct] = __builtin_amdgcn_mfma_f32_16x16x32_bf16(a, bb, oacc[ct], 0, 0, 0);
      }
    }
    if ((lane >> 4) == 0) {
#pragma unroll
      for (int ct = 0; ct < 8; ++ct) {
        int c = wave * 128 + ct * 16 + (lane & 15);
        float bov = bo[c];
#pragma unroll
        for (int reg = 0; reg < 2; ++reg)   // rows n0, n0+1 only
          out[(size_t)(b * Nn + n0 + reg) * 256 + c] = oacc[ct][reg] + bov;
      }
    }
  }
}

extern "C" void kernel_launch(void* const* d_in, const int* in_sizes, int n_in,
                              void* d_out, int out_size, void* d_ws, size_t ws_size,
                              hipStream_t stream) {
  const float* query = (const float*)d_in[0];
  const float* key_  = (const float*)d_in[1];
  const float* value = (const float*)d_in[2];
  const float* lnq_g = (const float*)d_in[3];
  const float* lnq_b = (const float*)d_in[4];
  const float* Wq    = (const float*)d_in[5];
  const float* bq    = (const float*)d_in[6];
  const float* lnk_g = (const float*)d_in[7];
  const float* lnk_b = (const float*)d_in[8];
  const float* Wk    = (const float*)d_in[9];
  const float* bk    = (const float*)d_in[10];
  const float* lnv_g = (const float*)d_in[11];
  const float* lnv_b = (const float*)d_in[12];
  const float* Wv    = (const float*)d_in[13];
  const float* bv    = (const float*)d_in[14];
  const float* Wo    = (const float*)d_in[15];
  const float* bo    = (const float*)d_in[16];
  short* wsb = (short*)d_ws;
  float* utf = (float*)((char*)d_ws + 262144 * sizeof(short));
  float* out = (float*)d_out;

  hipLaunchKernelGGL(prep_weights, dim3(256), dim3(256), 0, stream,
                     Wq, Wk, Wv, Wo, lnq_g, lnk_g, lnv_g, wsb);
  hipLaunchKernelGGL(prep_ut, dim3(3, 16), dim3(256), 0, stream,
                     Wq, Wk, Wv, lnq_g, lnq_b, bq, lnk_g, lnk_b, bk,
                     lnv_g, lnv_b, bv, utf);
  hipLaunchKernelGGL(geo_attn_main, dim3(Bb * (Nn / 2)), dim3(128), 0, stream,
                     query, key_, value, bo, wsb, utf, out);
}

// Round 16
// 267.821 us; speedup vs baseline: 1.9674x; 1.9674x over previous
//
#include <hip/hip_runtime.h>

// Problem dims (fixed)
constexpr int Bb = 2, Nn = 8192;
constexpr float SCALE = 0.17677669529663687f;  // 32^-0.5

typedef __attribute__((ext_vector_type(8))) short bf16x8;
typedef __attribute__((ext_vector_type(4))) float f32x4;

__device__ inline unsigned short f2bf(float f) {
  unsigned u = __float_as_uint(f);
  u = (u + 0x7fffu + ((u >> 16) & 1u)) >> 16;
  return (unsigned short)u;
}
__device__ inline float bf2f(short h) {
  return __uint_as_float(((unsigned)(unsigned short)h) << 16);
}
__device__ inline void wait_lds() {
  asm volatile("s_waitcnt lgkmcnt(0)" ::: "memory");
}

// ---------------- prep: (W .* g) fp32 -> bf16 MFMA-B-fragment layout ----------------
__global__ void prep_weights(const float* __restrict__ Wq, const float* __restrict__ Wk,
                             const float* __restrict__ Wv, const float* __restrict__ Wo,
                             const float* __restrict__ gq, const float* __restrict__ gk,
                             const float* __restrict__ gv, short* __restrict__ wsb) {
  int idx = blockIdx.x * 256 + threadIdx.x;   // 0..65535
  int j = idx & 7;
  int lane = (idx >> 3) & 63;
  int ks = (idx >> 9) & 7;
  int nt = idx >> 12;
  int co = nt * 16 + (lane & 15);
  int ci = ks * 32 + (lane >> 4) * 8 + j;
  int src = co * 256 + ci;
  wsb[idx]          = (short)f2bf(Wq[src] * gq[ci]);
  wsb[65536 + idx]  = (short)f2bf(Wk[src] * gk[ci]);
  wsb[131072 + idx] = (short)f2bf(Wv[src] * gv[ci]);
  wsb[196608 + idx] = (short)f2bf(Wo[src]);
}

// LN-fold vectors: u[o] = sum_c W[o][c]*g[c]; t[o] = sum_c W[o][c]*b[c] + bias[o]
__global__ void prep_ut(const float* __restrict__ Wq, const float* __restrict__ Wk,
                        const float* __restrict__ Wv,
                        const float* __restrict__ gq, const float* __restrict__ bq_ln,
                        const float* __restrict__ bq,
                        const float* __restrict__ gk, const float* __restrict__ bk_ln,
                        const float* __restrict__ bk,
                        const float* __restrict__ gv, const float* __restrict__ bv_ln,
                        const float* __restrict__ bv, float* __restrict__ utf) {
  const float *W, *g, *bl, *bias;
  float* dst;
  if (blockIdx.x == 0)      { W = Wq; g = gq; bl = bq_ln; bias = bq; dst = utf; }
  else if (blockIdx.x == 1) { W = Wk; g = gk; bl = bk_ln; bias = bk; dst = utf + 512; }
  else                      { W = Wv; g = gv; bl = bv_ln; bias = bv; dst = utf + 1024; }
  int o = blockIdx.y * 16 + (threadIdx.x >> 4);
  int cl = threadIdx.x & 15;
  float au = 0.f, at = 0.f;
#pragma unroll
  for (int j = 0; j < 4; ++j) {
    float4 w4 = *(const float4*)(W + o * 256 + cl * 16 + j * 4);
    float4 g4 = *(const float4*)(g + cl * 16 + j * 4);
    float4 b4 = *(const float4*)(bl + cl * 16 + j * 4);
    au = fmaf(w4.x, g4.x, fmaf(w4.y, g4.y, fmaf(w4.z, g4.z, fmaf(w4.w, g4.w, au))));
    at = fmaf(w4.x, b4.x, fmaf(w4.y, b4.y, fmaf(w4.z, b4.z, fmaf(w4.w, b4.w, at))));
  }
#pragma unroll
  for (int m = 1; m <= 8; m <<= 1) {
    au += __shfl_xor(au, m, 64);
    at += __shfl_xor(at, m, 64);
  }
  if (cl == 0) {
    dst[o] = au;
    dst[256 + o] = at + bias[o];
  }
}

// Cast a raw fp32 row to bf16 into the swizzled tile. Rows fully independent.
__device__ inline void store_row(const float4 v, int row, char* S, int lane) {
  ushort4 o;
  o.x = f2bf(v.x); o.y = f2bf(v.y); o.z = f2bf(v.z); o.w = f2bf(v.w);
  *(ushort4*)(S + row * 512 + ((lane * 8) ^ ((row & 7) << 4))) = o;
}

// Lane-parallel stats for 16 just-staged rows (R9-proven): 4 lanes/row from LDS bf16.
__device__ inline void stats16(const char* S, char* ST, int rbase, int lane) {
  wait_lds();   // own ds_writes drained
  int r = rbase + (lane >> 2);
  int q = lane & 3;
  const char* base = S + r * 512;
  int swz = (r & 7) << 4;
  float s = 0.f, ss = 0.f;
#pragma unroll
  for (int j = 0; j < 8; ++j) {
    bf16x8 x = *(const bf16x8*)(base + ((q * 128 + j * 16) ^ swz));
#pragma unroll
    for (int e = 0; e < 8; ++e) {
      float f = bf2f(x[e]);
      s += f;
      ss = fmaf(f, f, ss);
    }
  }
  s  += __shfl_xor(s, 1, 64);  ss += __shfl_xor(ss, 1, 64);
  s  += __shfl_xor(s, 2, 64);  ss += __shfl_xor(ss, 2, 64);
  float mu   = s * (1.0f / 256.0f);
  float var  = ss * (1.0f / 256.0f) - mu * mu;
  float rstd = rsqrtf(var + 1e-5f);
  if (q == 0) {
    float* d = (float*)(ST + r * 8);
    d[0] = rstd;
    d[1] = rstd * mu;
  }
}

// q-row staging keeps the precise in-register shuffle stats (1 row/wave).
__device__ inline void stage_row_q(const float4 v, int row, char* S, float* STrow, int lane) {
  ushort4 o;
  o.x = f2bf(v.x); o.y = f2bf(v.y); o.z = f2bf(v.z); o.w = f2bf(v.w);
  *(ushort4*)(S + row * 512 + ((lane * 8) ^ ((row & 7) << 4))) = o;
  float s  = v.x + v.y + v.z + v.w;
  float ss = fmaf(v.x, v.x, fmaf(v.y, v.y, fmaf(v.z, v.z, v.w * v.w)));
#pragma unroll
  for (int m = 32; m >= 1; m >>= 1) {
    s  += __shfl_xor(s, m, 64);
    ss += __shfl_xor(ss, m, 64);
  }
  float mu   = s * (1.0f / 256.0f);
  float var  = ss * (1.0f / 256.0f) - mu * mu;
  float rstd = rsqrtf(var + 1e-5f);
  if (lane == 0) { STrow[0] = rstd; STrow[1] = rstd * mu; }
}

// 64x256x256 projection on RAW bf16 rows with LN-fold epilogue — SINGLE pass:
// fragments read ONCE (bb held in regs across all 4 row-groups), acc = 64 regs.
// Halves B-fragment L2 traffic vs the two-pass version (the R15-measured bottleneck).
// In-place: MFMA reads all rows -> barrier -> epilogue overwrites rows.
__device__ inline void proj64_ln(char* S, const char* ST, const short* __restrict__ WB,
                                 const float* __restrict__ u, const float* __restrict__ t,
                                 int wave, int lane) {
  f32x4 acc[4][4] = {};
#pragma unroll
  for (int ks = 0; ks < 8; ++ks) {
    bf16x8 bb[4];
#pragma unroll
    for (int ntl = 0; ntl < 4; ++ntl)
      bb[ntl] = *(const bf16x8*)(WB + (((wave * 4 + ntl) * 8 + ks) * 64 + lane) * 8);
#pragma unroll
    for (int mt = 0; mt < 4; ++mt) {
      int row = mt * 16 + (lane & 15);
      bf16x8 a = *(const bf16x8*)(S + row * 512 +
                                  ((ks * 64 + (lane >> 4) * 16) ^ ((row & 7) << 4)));
#pragma unroll
      for (int ntl = 0; ntl < 4; ++ntl)
        acc[mt][ntl] = __builtin_amdgcn_mfma_f32_16x16x32_bf16(a, bb[ntl], acc[mt][ntl], 0, 0, 0);
    }
  }
  __syncthreads();   // all waves done reading staged rows; in-place overwrite safe
#pragma unroll
  for (int ntl = 0; ntl < 4; ++ntl) {
    int c = wave * 64 + ntl * 16 + (lane & 15);
    float uc = u[c];
    float tc = t[c];
#pragma unroll
    for (int mt = 0; mt < 4; ++mt)
#pragma unroll
      for (int reg = 0; reg < 4; ++reg) {
        int r = mt * 16 + (lane >> 4) * 4 + reg;
        float2 st = *(const float2*)(ST + r * 8);
        float val = fmaf(st.x, acc[mt][ntl][reg], fmaf(-st.y, uc, tc));
        *(unsigned short*)(S + r * 512 + ((c * 2) ^ ((r & 7) << 4))) = f2bf(val);
      }
  }
  __syncthreads();     // full projection visible
}

__global__ __launch_bounds__(256, 2) void geo_attn_main(
    const float* __restrict__ query, const float* __restrict__ key_,
    const float* __restrict__ value, const float* __restrict__ bo,
    const short* __restrict__ wsb, const float* __restrict__ utf,
    float* __restrict__ out) {
  __shared__ char smem[37888];
  char* S   = smem;           // [64][512B] swizzled bf16; rows 0-3 double as q / attn-out A-tile
  char* PR  = smem + 32768;   // [16][32] f32 probs (probs[k][g], g = nl*8+h)
  char* QL  = smem + 34816;   // [4][512B] q_proj bf16, plain layout
  char* ST  = smem + 36864;   // [64] float2 row stats (rstd, rstd*mu)
  char* STQ = smem + 37376;   // [4]  float2 q row stats

  const int tid = threadIdx.x;
  const int lane = tid & 63;
  const int wave = tid >> 6;
  const int blk = blockIdx.x;
  const int b = blk >> 11;
  const int n0 = (blk & 2047) * 4;

  const short* WqB = wsb;
  const short* WkB = wsb + 65536;
  const short* WvB = wsb + 131072;
  const short* WoB = wsb + 196608;
  const float* uq = utf;        const float* tq = utf + 256;
  const float* uk = utf + 512;  const float* tk = utf + 768;
  const float* uv = utf + 1024; const float* tv = utf + 1280;

  const float* ksrc = key_  + (size_t)((b * Nn + n0) * 16) * 256;
  const float* vsrc = value + (size_t)((b * Nn + n0) * 16) * 256;
  const int rbase = wave * 16;

  // ---- Issue K batch 0 (4 rows); hidden under q-stage + q-proj ----
  float4 kcur[4];
#pragma unroll
  for (int i = 0; i < 4; ++i)
    kcur[i] = *(const float4*)(ksrc + (size_t)(rbase + i) * 256 + lane * 4);

  // ---- Phase 1: q-stage (bf16 + precise stats), one row per wave ----
  {
    float4 v = *(const float4*)(query + (size_t)(b * Nn + n0 + wave) * 256 + lane * 4);
    stage_row_q(v, wave, S, (float*)(STQ + wave * 8), lane);
  }
  __syncthreads();

  // ---- Phase 2: q-proj mini-GEMM (LN-fold epilogue) -> QL ----
  {
    f32x4 qacc[4] = {};
#pragma unroll
    for (int ks = 0; ks < 8; ++ks) {
      int arow = lane & 15;
      bf16x8 a = *(const bf16x8*)(S + arow * 512 +
                                  ((ks * 64 + (lane >> 4) * 16) ^ ((arow & 7) << 4)));
#pragma unroll
      for (int ntl = 0; ntl < 4; ++ntl) {
        bf16x8 bb = *(const bf16x8*)(WqB + (((wave * 4 + ntl) * 8 + ks) * 64 + lane) * 8);
        qacc[ntl] = __builtin_amdgcn_mfma_f32_16x16x32_bf16(a, bb, qacc[ntl], 0, 0, 0);
      }
    }
    if ((lane >> 4) == 0) {
#pragma unroll
      for (int ntl = 0; ntl < 4; ++ntl) {
        int c = wave * 64 + ntl * 16 + (lane & 15);
        float uc = uq[c];
        float tc = tq[c];
#pragma unroll
        for (int reg = 0; reg < 4; ++reg) {
          float2 stq = *(const float2*)(STQ + reg * 8);
          float val = fmaf(stq.x, qacc[ntl][reg], fmaf(-stq.y, uc, tc));
          *(unsigned short*)(QL + reg * 512 + c * 2) = f2bf(val);
        }
      }
    }
  }
  __syncthreads();   // S reads done; K-stage may overwrite

  // ---- Phase 3: K-stage (16 independent cvt-store rows) + lane-parallel stats ----
  {
#pragma unroll
    for (int i = 0; i < 4; ++i) store_row(kcur[i], rbase + i, S, lane);
#pragma unroll
    for (int i = 4; i < 16; ++i) {
      float4 v = *(const float4*)(ksrc + (size_t)(rbase + i) * 256 + lane * 4);
      store_row(v, rbase + i, S, lane);
    }
    stats16(S, ST, rbase, lane);
  }
  __syncthreads();

  // ---- Phase 4: K-proj with LN-fold (single pass, fragments read once) ----
  proj64_ln(S, ST, WkB, uk, tk, wave, lane);

  // ---- Issue V batch 0: hidden under logits+softmax ----
  float4 vcur[4];
#pragma unroll
  for (int i = 0; i < 4; ++i)
    vcur[i] = *(const float4*)(vsrc + (size_t)(rbase + i) * 256 + lane * 4);

  // ---- Phase 5: logits + fused softmax (8-lane groups) -> PR ----
  {
    int g = tid >> 3;         // 0..31
    int nl = g >> 3, h = g & 7;
    int k0 = (tid & 7) * 2;
    float a0 = 0.f, a1 = 0.f;
#pragma unroll
    for (int kk = 0; kk < 2; ++kk) {
      int row = nl * 16 + k0 + kk;
      float a = 0.f;
#pragma unroll
      for (int j4 = 0; j4 < 4; ++j4) {
        bf16x8 qq = *(const bf16x8*)(QL + nl * 512 + h * 64 + j4 * 16);
        bf16x8 kv = *(const bf16x8*)(S + row * 512 +
                                     ((h * 64 + j4 * 16) ^ ((row & 7) << 4)));
#pragma unroll
        for (int j = 0; j < 8; ++j) a = fmaf(bf2f(qq[j]), bf2f(kv[j]), a);
      }
      if (kk == 0) a0 = a * SCALE; else a1 = a * SCALE;
    }
    float m = fmaxf(a0, a1);
#pragma unroll
    for (int msk = 1; msk <= 4; msk <<= 1) m = fmaxf(m, __shfl_xor(m, msk, 64));
    float e0 = __expf(a0 - m), e1 = __expf(a1 - m);
    float ssum = e0 + e1;
#pragma unroll
    for (int msk = 1; msk <= 4; msk <<= 1) ssum += __shfl_xor(ssum, msk, 64);
    float inv = 1.0f / ssum;
    *(float*)(PR + ((k0)     * 32 + g) * 4) = e0 * inv;
    *(float*)(PR + ((k0 + 1) * 32 + g) * 4) = e1 * inv;
  }
  __syncthreads();   // S (K-proj) reads done; V-stage may overwrite

  // ---- Phase 6: V-stage (independent rows) + lane-parallel stats ----
  {
#pragma unroll
    for (int i = 0; i < 4; ++i) store_row(vcur[i], rbase + i, S, lane);
#pragma unroll
    for (int i = 4; i < 16; ++i) {
      float4 v = *(const float4*)(vsrc + (size_t)(rbase + i) * 256 + lane * 4);
      store_row(v, rbase + i, S, lane);
    }
    stats16(S, ST, rbase, lane);
  }
  __syncthreads();

  // ---- Phase 7: V-proj with LN-fold (single pass, fragments read once) ----
  proj64_ln(S, ST, WvB, uv, tv, wave, lane);

  // ---- Phase 8: PV -> regs ----
  float o0 = 0.f, o1 = 0.f, o2 = 0.f, o3 = 0.f;
  {
    int nl = wave;
    int c0 = lane * 4;
    int h = c0 >> 5;
#pragma unroll
    for (int k = 0; k < 16; ++k) {
      float p = *(const float*)(PR + (k * 32 + nl * 8 + h) * 4);
      int row = nl * 16 + k;
      ushort4 vv = *(const ushort4*)(S + row * 512 + ((c0 * 2) ^ ((row & 7) << 4)));
      o0 = fmaf(p, bf2f((short)vv.x), o0);
      o1 = fmaf(p, bf2f((short)vv.y), o1);
      o2 = fmaf(p, bf2f((short)vv.z), o2);
      o3 = fmaf(p, bf2f((short)vv.w), o3);
    }
  }
  __syncthreads();   // all S reads done before overwrite
  {
    int nl = wave;
    int c0 = lane * 4;
    ushort4 ob;
    ob.x = f2bf(o0); ob.y = f2bf(o1); ob.z = f2bf(o2); ob.w = f2bf(o3);
    *(ushort4*)(S + nl * 512 + ((c0 * 2) ^ ((nl & 7) << 4))) = ob;
  }
  __syncthreads();

  // ---- Phase 9: out-proj GEMM + store (plain bias; A rows 4-15 garbage -> discarded) ----
  {
    f32x4 oacc[4] = {};
#pragma unroll
    for (int ks = 0; ks < 8; ++ks) {
      int arow = lane & 15;
      bf16x8 a = *(const bf16x8*)(S + arow * 512 +
                                  ((ks * 64 + (lane >> 4) * 16) ^ ((arow & 7) << 4)));
#pragma unroll
      for (int ntl = 0; ntl < 4; ++ntl) {
        bf16x8 bb = *(const bf16x8*)(WoB + (((wave * 4 + ntl) * 8 + ks) * 64 + lane) * 8);
        oacc[ntl] = __builtin_amdgcn_mfma_f32_16x16x32_bf16(a, bb, oacc[ntl], 0, 0, 0);
      }
    }
    if ((lane >> 4) == 0) {
#pragma unroll
      for (int ntl = 0; ntl < 4; ++ntl) {
        int c = wave * 64 + ntl * 16 + (lane & 15);
        float bov = bo[c];
#pragma unroll
        for (int reg = 0; reg < 4; ++reg)
          out[(size_t)(b * Nn + n0 + reg) * 256 + c] = oacc[ntl][reg] + bov;
      }
    }
  }
}

extern "C" void kernel_launch(void* const* d_in, const int* in_sizes, int n_in,
                              void* d_out, int out_size, void* d_ws, size_t ws_size,
                              hipStream_t stream) {
  const float* query = (const float*)d_in[0];
  const float* key_  = (const float*)d_in[1];
  const float* value = (const float*)d_in[2];
  const float* lnq_g = (const float*)d_in[3];
  const float* lnq_b = (const float*)d_in[4];
  const float* Wq    = (const float*)d_in[5];
  const float* bq    = (const float*)d_in[6];
  const float* lnk_g = (const float*)d_in[7];
  const float* lnk_b = (const float*)d_in[8];
  const float* Wk    = (const float*)d_in[9];
  const float* bk    = (const float*)d_in[10];
  const float* lnv_g = (const float*)d_in[11];
  const float* lnv_b = (const float*)d_in[12];
  const float* Wv    = (const float*)d_in[13];
  const float* bv    = (const float*)d_in[14];
  const float* Wo    = (const float*)d_in[15];
  const float* bo    = (const float*)d_in[16];
  short* wsb = (short*)d_ws;
  float* utf = (float*)((char*)d_ws + 262144 * sizeof(short));
  float* out = (float*)d_out;

  hipLaunchKernelGGL(prep_weights, dim3(256), dim3(256), 0, stream,
                     Wq, Wk, Wv, Wo, lnq_g, lnk_g, lnv_g, wsb);
  hipLaunchKernelGGL(prep_ut, dim3(3, 16), dim3(256), 0, stream,
                     Wq, Wk, Wv, lnq_g, lnq_b, bq, lnk_g, lnk_b, bk,
                     lnv_g, lnv_b, bv, utf);
  hipLaunchKernelGGL(geo_attn_main, dim3(Bb * (Nn / 4)), dim3(256), 0, stream,
                     query, key_, value, bo, wsb, utf, out);
}

// Round 17
// 231.178 us; speedup vs baseline: 2.2793x; 1.1585x over previous
//
#include <hip/hip_runtime.h>

// Problem dims (fixed)
constexpr int Bb = 2, Nn = 8192;
constexpr float SCALE = 0.17677669529663687f;  // 32^-0.5

typedef __attribute__((ext_vector_type(8))) short bf16x8;
typedef __attribute__((ext_vector_type(4))) float f32x4;

__device__ inline unsigned short f2bf(float f) {
  unsigned u = __float_as_uint(f);
  u = (u + 0x7fffu + ((u >> 16) & 1u)) >> 16;
  return (unsigned short)u;
}
__device__ inline float bf2f(short h) {
  return __uint_as_float(((unsigned)(unsigned short)h) << 16);
}
__device__ inline void wait_lds() {
  asm volatile("s_waitcnt lgkmcnt(0)" ::: "memory");
}

// ---------------- prep: (W .* g) fp32 -> bf16 MFMA-B-fragment layout ----------------
__global__ void prep_weights(const float* __restrict__ Wq, const float* __restrict__ Wk,
                             const float* __restrict__ Wv, const float* __restrict__ Wo,
                             const float* __restrict__ gq, const float* __restrict__ gk,
                             const float* __restrict__ gv, short* __restrict__ wsb) {
  int idx = blockIdx.x * 256 + threadIdx.x;   // 0..65535
  int j = idx & 7;
  int lane = (idx >> 3) & 63;
  int ks = (idx >> 9) & 7;
  int nt = idx >> 12;
  int co = nt * 16 + (lane & 15);
  int ci = ks * 32 + (lane >> 4) * 8 + j;
  int src = co * 256 + ci;
  wsb[idx]          = (short)f2bf(Wq[src] * gq[ci]);
  wsb[65536 + idx]  = (short)f2bf(Wk[src] * gk[ci]);
  wsb[131072 + idx] = (short)f2bf(Wv[src] * gv[ci]);
  wsb[196608 + idx] = (short)f2bf(Wo[src]);
}

// LN-fold vectors: u[o] = sum_c W[o][c]*g[c]; t[o] = sum_c W[o][c]*b[c] + bias[o]
__global__ void prep_ut(const float* __restrict__ Wq, const float* __restrict__ Wk,
                        const float* __restrict__ Wv,
                        const float* __restrict__ gq, const float* __restrict__ bq_ln,
                        const float* __restrict__ bq,
                        const float* __restrict__ gk, const float* __restrict__ bk_ln,
                        const float* __restrict__ bk,
                        const float* __restrict__ gv, const float* __restrict__ bv_ln,
                        const float* __restrict__ bv, float* __restrict__ utf) {
  const float *W, *g, *bl, *bias;
  float* dst;
  if (blockIdx.x == 0)      { W = Wq; g = gq; bl = bq_ln; bias = bq; dst = utf; }
  else if (blockIdx.x == 1) { W = Wk; g = gk; bl = bk_ln; bias = bk; dst = utf + 512; }
  else                      { W = Wv; g = gv; bl = bv_ln; bias = bv; dst = utf + 1024; }
  int o = blockIdx.y * 16 + (threadIdx.x >> 4);
  int cl = threadIdx.x & 15;
  float au = 0.f, at = 0.f;
#pragma unroll
  for (int j = 0; j < 4; ++j) {
    float4 w4 = *(const float4*)(W + o * 256 + cl * 16 + j * 4);
    float4 g4 = *(const float4*)(g + cl * 16 + j * 4);
    float4 b4 = *(const float4*)(bl + cl * 16 + j * 4);
    au = fmaf(w4.x, g4.x, fmaf(w4.y, g4.y, fmaf(w4.z, g4.z, fmaf(w4.w, g4.w, au))));
    at = fmaf(w4.x, b4.x, fmaf(w4.y, b4.y, fmaf(w4.z, b4.z, fmaf(w4.w, b4.w, at))));
  }
#pragma unroll
  for (int m = 1; m <= 8; m <<= 1) {
    au += __shfl_xor(au, m, 64);
    at += __shfl_xor(at, m, 64);
  }
  if (cl == 0) {
    dst[o] = au;
    dst[256 + o] = at + bias[o];
  }
}

// Cast a raw fp32 row to bf16 into the swizzled tile. Rows fully independent.
__device__ inline void store_row(const float4 v, int row, char* S, int lane) {
  ushort4 o;
  o.x = f2bf(v.x); o.y = f2bf(v.y); o.z = f2bf(v.z); o.w = f2bf(v.w);
  *(ushort4*)(S + row * 512 + ((lane * 8) ^ ((row & 7) << 4))) = o;
}

// Lane-parallel stats for 16 just-staged rows (R9-proven): 4 lanes/row from LDS bf16.
__device__ inline void stats16(const char* S, char* ST, int rbase, int lane) {
  int r = rbase + (lane >> 2);
  int q = lane & 3;
  const char* base = S + r * 512;
  int swz = (r & 7) << 4;
  float s = 0.f, ss = 0.f;
#pragma unroll
  for (int j = 0; j < 8; ++j) {
    bf16x8 x = *(const bf16x8*)(base + ((q * 128 + j * 16) ^ swz));
#pragma unroll
    for (int e = 0; e < 8; ++e) {
      float f = bf2f(x[e]);
      s += f;
      ss = fmaf(f, f, ss);
    }
  }
  s  += __shfl_xor(s, 1, 64);  ss += __shfl_xor(ss, 1, 64);
  s  += __shfl_xor(s, 2, 64);  ss += __shfl_xor(ss, 2, 64);
  float mu   = s * (1.0f / 256.0f);
  float var  = ss * (1.0f / 256.0f) - mu * mu;
  float rstd = rsqrtf(var + 1e-5f);
  if (q == 0) {
    float* d = (float*)(ST + r * 8);
    d[0] = rstd;
    d[1] = rstd * mu;
  }
}

// q-row staging keeps the precise in-register shuffle stats.
__device__ inline void stage_row_q(const float4 v, int row, char* S, float* STrow, int lane) {
  ushort4 o;
  o.x = f2bf(v.x); o.y = f2bf(v.y); o.z = f2bf(v.z); o.w = f2bf(v.w);
  *(ushort4*)(S + row * 512 + ((lane * 8) ^ ((row & 7) << 4))) = o;
  float s  = v.x + v.y + v.z + v.w;
  float ss = fmaf(v.x, v.x, fmaf(v.y, v.y, fmaf(v.z, v.z, v.w * v.w)));
#pragma unroll
  for (int m = 32; m >= 1; m >>= 1) {
    s  += __shfl_xor(s, m, 64);
    ss += __shfl_xor(ss, m, 64);
  }
  float mu   = s * (1.0f / 256.0f);
  float var  = ss * (1.0f / 256.0f) - mu * mu;
  float rstd = rsqrtf(var + 1e-5f);
  if (lane == 0) { STrow[0] = rstd; STrow[1] = rstd * mu; }
}

// 128x256x256 projection on RAW bf16 rows with LN-fold epilogue; four row-passes of
// 32 rows, acc = 32 regs (R9-proven per-pass pattern). In-place over S.
__device__ inline void proj128_ln(char* S, const char* ST, const short* __restrict__ WB,
                                  const float* __restrict__ u, const float* __restrict__ t,
                                  int wave, int lane) {
#pragma unroll
  for (int p = 0; p < 4; ++p) {
    f32x4 acc[2][4] = {};
#pragma unroll
    for (int ks = 0; ks < 8; ++ks) {
      bf16x8 bb[4];
#pragma unroll
      for (int ntl = 0; ntl < 4; ++ntl)
        bb[ntl] = *(const bf16x8*)(WB + (((wave * 4 + ntl) * 8 + ks) * 64 + lane) * 8);
#pragma unroll
      for (int mt = 0; mt < 2; ++mt) {
        int row = p * 32 + mt * 16 + (lane & 15);
        bf16x8 a = *(const bf16x8*)(S + row * 512 +
                                    ((ks * 64 + (lane >> 4) * 16) ^ ((row & 7) << 4)));
#pragma unroll
        for (int ntl = 0; ntl < 4; ++ntl)
          acc[mt][ntl] = __builtin_amdgcn_mfma_f32_16x16x32_bf16(a, bb[ntl], acc[mt][ntl], 0, 0, 0);
      }
    }
    __syncthreads();   // all waves done reading staged rows p*32..p*32+31
    float2 st[2][4];
#pragma unroll
    for (int mt = 0; mt < 2; ++mt)
#pragma unroll
      for (int reg = 0; reg < 4; ++reg) {
        int r = p * 32 + mt * 16 + (lane >> 4) * 4 + reg;
        st[mt][reg] = *(const float2*)(ST + r * 8);
      }
#pragma unroll
    for (int ntl = 0; ntl < 4; ++ntl) {
      int c = wave * 64 + ntl * 16 + (lane & 15);
      float uc = u[c];
      float tc = t[c];
#pragma unroll
      for (int mt = 0; mt < 2; ++mt)
#pragma unroll
        for (int reg = 0; reg < 4; ++reg) {
          int r = p * 32 + mt * 16 + (lane >> 4) * 4 + reg;
          float val = fmaf(st[mt][reg].x, acc[mt][ntl][reg], fmaf(-st[mt][reg].y, uc, tc));
          *(unsigned short*)(S + r * 512 + ((c * 2) ^ ((r & 7) << 4))) = f2bf(val);
        }
    }
  }
  __syncthreads();     // full projection visible
}

__global__ __launch_bounds__(256, 2) void geo_attn_main(
    const float* __restrict__ query, const float* __restrict__ key_,
    const float* __restrict__ value, const float* __restrict__ bo,
    const short* __restrict__ wsb, const float* __restrict__ utf,
    float* __restrict__ out) {
  __shared__ char smem[74816];
  char* S   = smem;           // [128][512B] swizzled bf16; rows 0-7 double as q / attn-out A-tile
  char* PR  = smem + 65536;   // [16][64] f32 probs (probs[k][g], g = nl*8+h, nl<8)
  char* QL  = smem + 69632;   // [8][512B] q_proj bf16, plain layout
  char* ST  = smem + 73728;   // [128] float2 row stats (rstd, rstd*mu)
  char* STQ = smem + 74752;   // [8]  float2 q row stats

  const int tid = threadIdx.x;
  const int lane = tid & 63;
  const int wave = tid >> 6;
  const int blk = blockIdx.x;
  const int b = blk >> 10;            // 1024 blocks per batch
  const int n0 = (blk & 1023) * 8;

  const short* WqB = wsb;
  const short* WkB = wsb + 65536;
  const short* WvB = wsb + 131072;
  const short* WoB = wsb + 196608;
  const float* uq = utf;        const float* tq = utf + 256;
  const float* uk = utf + 512;  const float* tk = utf + 768;
  const float* uv = utf + 1024; const float* tv = utf + 1280;

  const float* ksrc = key_  + (size_t)((b * Nn + n0) * 16) * 256;
  const float* vsrc = value + (size_t)((b * Nn + n0) * 16) * 256;
  const int rbase = wave * 32;        // this wave's 32 staging rows

  // ---- Issue K batch 0 (4 rows); hidden under q-stage + q-proj ----
  float4 kcur[4];
#pragma unroll
  for (int i = 0; i < 4; ++i)
    kcur[i] = *(const float4*)(ksrc + (size_t)(rbase + i) * 256 + lane * 4);

  // ---- Phase 1: q-stage (bf16 + precise stats), two rows per wave ----
  {
#pragma unroll
    for (int i = 0; i < 2; ++i) {
      int row = wave * 2 + i;
      float4 v = *(const float4*)(query + (size_t)(b * Nn + n0 + row) * 256 + lane * 4);
      stage_row_q(v, row, S, (float*)(STQ + row * 8), lane);
    }
  }
  __syncthreads();

  // ---- Phase 2: q-proj mini-GEMM (LN-fold epilogue) -> QL rows 0-7 ----
  {
    f32x4 qacc[4] = {};
#pragma unroll
    for (int ks = 0; ks < 8; ++ks) {
      int arow = lane & 15;
      bf16x8 a = *(const bf16x8*)(S + arow * 512 +
                                  ((ks * 64 + (lane >> 4) * 16) ^ ((arow & 7) << 4)));
#pragma unroll
      for (int ntl = 0; ntl < 4; ++ntl) {
        bf16x8 bb = *(const bf16x8*)(WqB + (((wave * 4 + ntl) * 8 + ks) * 64 + lane) * 8);
        qacc[ntl] = __builtin_amdgcn_mfma_f32_16x16x32_bf16(a, bb, qacc[ntl], 0, 0, 0);
      }
    }
    if ((lane >> 4) < 2) {
#pragma unroll
      for (int ntl = 0; ntl < 4; ++ntl) {
        int c = wave * 64 + ntl * 16 + (lane & 15);
        float uc = uq[c];
        float tc = tq[c];
#pragma unroll
        for (int reg = 0; reg < 4; ++reg) {
          int r = (lane >> 4) * 4 + reg;      // rows 0-7
          float2 stq = *(const float2*)(STQ + r * 8);
          float val = fmaf(stq.x, qacc[ntl][reg], fmaf(-stq.y, uc, tc));
          *(unsigned short*)(QL + r * 512 + c * 2) = f2bf(val);
        }
      }
    }
  }
  __syncthreads();   // QL visible; S free for K-stage

  // ---- Phase 3: K-stage (32 independent cvt-store rows/wave) + stats ----
  {
#pragma unroll
    for (int i = 0; i < 4; ++i) store_row(kcur[i], rbase + i, S, lane);
#pragma unroll
    for (int i = 4; i < 32; ++i) {
      float4 v = *(const float4*)(ksrc + (size_t)(rbase + i) * 256 + lane * 4);
      store_row(v, rbase + i, S, lane);
    }
    wait_lds();
    stats16(S, ST, rbase, lane);
    stats16(S, ST, rbase + 16, lane);
  }
  __syncthreads();

  // ---- Phase 4: K-proj with LN-fold (four row-passes, in-place) ----
  proj128_ln(S, ST, WkB, uk, tk, wave, lane);

  // ---- Issue V batch 0: hidden under logits+softmax ----
  float4 vcur[4];
#pragma unroll
  for (int i = 0; i < 4; ++i)
    vcur[i] = *(const float4*)(vsrc + (size_t)(rbase + i) * 256 + lane * 4);

  // ---- Phase 5: logits + fused softmax (4-lane groups, 4 k/thread) -> PR ----
  {
    int g = tid >> 2;         // 0..63 = nl*8 + h
    int nl = g >> 3, h = g & 7;
    int k0 = (tid & 3) * 4;
    float a[4];
#pragma unroll
    for (int kk = 0; kk < 4; ++kk) {
      int row = nl * 16 + k0 + kk;
      float acc = 0.f;
#pragma unroll
      for (int j4 = 0; j4 < 4; ++j4) {
        bf16x8 qq = *(const bf16x8*)(QL + nl * 512 + h * 64 + j4 * 16);
        bf16x8 kv = *(const bf16x8*)(S + row * 512 +
                                     ((h * 64 + j4 * 16) ^ ((row & 7) << 4)));
#pragma unroll
        for (int j = 0; j < 8; ++j) acc = fmaf(bf2f(qq[j]), bf2f(kv[j]), acc);
      }
      a[kk] = acc * SCALE;
    }
    float m = fmaxf(fmaxf(a[0], a[1]), fmaxf(a[2], a[3]));
#pragma unroll
    for (int msk = 1; msk <= 2; msk <<= 1) m = fmaxf(m, __shfl_xor(m, msk, 64));
    float e[4];
    float ssum = 0.f;
#pragma unroll
    for (int kk = 0; kk < 4; ++kk) { e[kk] = __expf(a[kk] - m); ssum += e[kk]; }
#pragma unroll
    for (int msk = 1; msk <= 2; msk <<= 1) ssum += __shfl_xor(ssum, msk, 64);
    float inv = 1.0f / ssum;
#pragma unroll
    for (int kk = 0; kk < 4; ++kk)
      *(float*)(PR + ((k0 + kk) * 64 + g) * 4) = e[kk] * inv;
  }
  __syncthreads();   // S (K-proj) reads done; V-stage may overwrite

  // ---- Phase 6: V-stage (32 rows/wave) + stats ----
  {
#pragma unroll
    for (int i = 0; i < 4; ++i) store_row(vcur[i], rbase + i, S, lane);
#pragma unroll
    for (int i = 4; i < 32; ++i) {
      float4 v = *(const float4*)(vsrc + (size_t)(rbase + i) * 256 + lane * 4);
      store_row(v, rbase + i, S, lane);
    }
    wait_lds();
    stats16(S, ST, rbase, lane);
    stats16(S, ST, rbase + 16, lane);
  }
  __syncthreads();

  // ---- Phase 7: V-proj with LN-fold (four row-passes, in-place) ----
  proj128_ln(S, ST, WvB, uv, tv, wave, lane);

  // ---- Phase 8: PV -> regs (2 positions per wave) ----
  float o[2][4];
#pragma unroll
  for (int pi = 0; pi < 2; ++pi) {
    int nl = wave * 2 + pi;
    int c0 = lane * 4;
    int h = c0 >> 5;
    float o0 = 0.f, o1 = 0.f, o2 = 0.f, o3 = 0.f;
#pragma unroll
    for (int k = 0; k < 16; ++k) {
      float p = *(const float*)(PR + (k * 64 + nl * 8 + h) * 4);
      int row = nl * 16 + k;
      ushort4 vv = *(const ushort4*)(S + row * 512 + ((c0 * 2) ^ ((row & 7) << 4)));
      o0 = fmaf(p, bf2f((short)vv.x), o0);
      o1 = fmaf(p, bf2f((short)vv.y), o1);
      o2 = fmaf(p, bf2f((short)vv.z), o2);
      o3 = fmaf(p, bf2f((short)vv.w), o3);
    }
    o[pi][0] = o0; o[pi][1] = o1; o[pi][2] = o2; o[pi][3] = o3;
  }
  __syncthreads();   // all S reads done before overwrite
  {
    int c0 = lane * 4;
#pragma unroll
    for (int pi = 0; pi < 2; ++pi) {
      int nl = wave * 2 + pi;
      ushort4 ob;
      ob.x = f2bf(o[pi][0]); ob.y = f2bf(o[pi][1]);
      ob.z = f2bf(o[pi][2]); ob.w = f2bf(o[pi][3]);
      *(ushort4*)(S + nl * 512 + ((c0 * 2) ^ ((nl & 7) << 4))) = ob;
    }
  }
  __syncthreads();

  // ---- Phase 9: out-proj GEMM + store (A rows 8-15 garbage -> discarded) ----
  {
    f32x4 oacc[4] = {};
#pragma unroll
    for (int ks = 0; ks < 8; ++ks) {
      int arow = lane & 15;
      bf16x8 a = *(const bf16x8*)(S + arow * 512 +
                                  ((ks * 64 + (lane >> 4) * 16) ^ ((arow & 7) << 4)));
#pragma unroll
      for (int ntl = 0; ntl < 4; ++ntl) {
        bf16x8 bb = *(const bf16x8*)(WoB + (((wave * 4 + ntl) * 8 + ks) * 64 + lane) * 8);
        oacc[ntl] = __builtin_amdgcn_mfma_f32_16x16x32_bf16(a, bb, oacc[ntl], 0, 0, 0);
      }
    }
    if ((lane >> 4) < 2) {
#pragma unroll
      for (int ntl = 0; ntl < 4; ++ntl) {
        int c = wave * 64 + ntl * 16 + (lane & 15);
        float bov = bo[c];
#pragma unroll
        for (int reg = 0; reg < 4; ++reg) {
          int r = (lane >> 4) * 4 + reg;    // rows 0-7
          out[(size_t)(b * Nn + n0 + r) * 256 + c] = oacc[ntl][reg] + bov;
        }
      }
    }
  }
}

extern "C" void kernel_launch(void* const* d_in, const int* in_sizes, int n_in,
                              void* d_out, int out_size, void* d_ws, size_t ws_size,
                              hipStream_t stream) {
  const float* query = (const float*)d_in[0];
  const float* key_  = (const float*)d_in[1];
  const float* value = (const float*)d_in[2];
  const float* lnq_g = (const float*)d_in[3];
  const float* lnq_b = (const float*)d_in[4];
  const float* Wq    = (const float*)d_in[5];
  const float* bq    = (const float*)d_in[6];
  const float* lnk_g = (const float*)d_in[7];
  const float* lnk_b = (const float*)d_in[8];
  const float* Wk    = (const float*)d_in[9];
  const float* bk    = (const float*)d_in[10];
  const float* lnv_g = (const float*)d_in[11];
  const float* lnv_b = (const float*)d_in[12];
  const float* Wv    = (const float*)d_in[13];
  const float* bv    = (const float*)d_in[14];
  const float* Wo    = (const float*)d_in[15];
  const float* bo    = (const float*)d_in[16];
  short* wsb = (short*)d_ws;
  float* utf = (float*)((char*)d_ws + 262144 * sizeof(short));
  float* out = (float*)d_out;

  hipLaunchKernelGGL(prep_weights, dim3(256), dim3(256), 0, stream,
                     Wq, Wk, Wv, Wo, lnq_g, lnk_g, lnv_g, wsb);
  hipLaunchKernelGGL(prep_ut, dim3(3, 16), dim3(256), 0, stream,
                     Wq, Wk, Wv, lnq_g, lnq_b, bq, lnk_g, lnk_b, bk,
                     lnv_g, lnv_b, bv, utf);
  hipLaunchKernelGGL(geo_attn_main, dim3(Bb * (Nn / 8)), dim3(256), 0, stream,
                     query, key_, value, bo, wsb, utf, out);
}

// Round 18
// 227.554 us; speedup vs baseline: 2.3156x; 1.0159x over previous
//
#include <hip/hip_runtime.h>

// Problem dims (fixed)
constexpr int Bb = 2, Nn = 8192;
constexpr float SCALE = 0.17677669529663687f;  // 32^-0.5

typedef __attribute__((ext_vector_type(8))) short bf16x8;
typedef __attribute__((ext_vector_type(4))) float f32x4;

__device__ inline unsigned short f2bf(float f) {
  unsigned u = __float_as_uint(f);
  u = (u + 0x7fffu + ((u >> 16) & 1u)) >> 16;
  return (unsigned short)u;
}
__device__ inline float bf2f(short h) {
  return __uint_as_float(((unsigned)(unsigned short)h) << 16);
}
__device__ inline void wait_lds() {
  asm volatile("s_waitcnt lgkmcnt(0)" ::: "memory");
}

// ---------------- prep: (W .* g) fp32 -> bf16 MFMA-B-fragment layout ----------------
__global__ void prep_weights(const float* __restrict__ Wq, const float* __restrict__ Wk,
                             const float* __restrict__ Wv, const float* __restrict__ Wo,
                             const float* __restrict__ gq, const float* __restrict__ gk,
                             const float* __restrict__ gv, short* __restrict__ wsb) {
  int idx = blockIdx.x * 256 + threadIdx.x;   // 0..65535
  int j = idx & 7;
  int lane = (idx >> 3) & 63;
  int ks = (idx >> 9) & 7;
  int nt = idx >> 12;
  int co = nt * 16 + (lane & 15);
  int ci = ks * 32 + (lane >> 4) * 8 + j;
  int src = co * 256 + ci;
  wsb[idx]          = (short)f2bf(Wq[src] * gq[ci]);
  wsb[65536 + idx]  = (short)f2bf(Wk[src] * gk[ci]);
  wsb[131072 + idx] = (short)f2bf(Wv[src] * gv[ci]);
  wsb[196608 + idx] = (short)f2bf(Wo[src]);
}

// LN-fold vectors: u[o] = sum_c W[o][c]*g[c]; t[o] = sum_c W[o][c]*b[c] + bias[o]
__global__ void prep_ut(const float* __restrict__ Wq, const float* __restrict__ Wk,
                        const float* __restrict__ Wv,
                        const float* __restrict__ gq, const float* __restrict__ bq_ln,
                        const float* __restrict__ bq,
                        const float* __restrict__ gk, const float* __restrict__ bk_ln,
                        const float* __restrict__ bk,
                        const float* __restrict__ gv, const float* __restrict__ bv_ln,
                        const float* __restrict__ bv, float* __restrict__ utf) {
  const float *W, *g, *bl, *bias;
  float* dst;
  if (blockIdx.x == 0)      { W = Wq; g = gq; bl = bq_ln; bias = bq; dst = utf; }
  else if (blockIdx.x == 1) { W = Wk; g = gk; bl = bk_ln; bias = bk; dst = utf + 512; }
  else                      { W = Wv; g = gv; bl = bv_ln; bias = bv; dst = utf + 1024; }
  int o = blockIdx.y * 16 + (threadIdx.x >> 4);
  int cl = threadIdx.x & 15;
  float au = 0.f, at = 0.f;
#pragma unroll
  for (int j = 0; j < 4; ++j) {
    float4 w4 = *(const float4*)(W + o * 256 + cl * 16 + j * 4);
    float4 g4 = *(const float4*)(g + cl * 16 + j * 4);
    float4 b4 = *(const float4*)(bl + cl * 16 + j * 4);
    au = fmaf(w4.x, g4.x, fmaf(w4.y, g4.y, fmaf(w4.z, g4.z, fmaf(w4.w, g4.w, au))));
    at = fmaf(w4.x, b4.x, fmaf(w4.y, b4.y, fmaf(w4.z, b4.z, fmaf(w4.w, b4.w, at))));
  }
#pragma unroll
  for (int m = 1; m <= 8; m <<= 1) {
    au += __shfl_xor(au, m, 64);
    at += __shfl_xor(at, m, 64);
  }
  if (cl == 0) {
    dst[o] = au;
    dst[256 + o] = at + bias[o];
  }
}

// Cast a raw fp32 row to bf16 into the swizzled tile. Rows fully independent.
__device__ inline void store_row(const float4 v, int row, char* S, int lane) {
  ushort4 o;
  o.x = f2bf(v.x); o.y = f2bf(v.y); o.z = f2bf(v.z); o.w = f2bf(v.w);
  *(ushort4*)(S + row * 512 + ((lane * 8) ^ ((row & 7) << 4))) = o;
}

// Lane-parallel stats for 16 just-staged rows: 4 lanes/row from LDS bf16.
__device__ inline void stats16(const char* S, char* ST, int rbase, int lane) {
  int r = rbase + (lane >> 2);
  int q = lane & 3;
  const char* base = S + r * 512;
  int swz = (r & 7) << 4;
  float s = 0.f, ss = 0.f;
#pragma unroll
  for (int j = 0; j < 8; ++j) {
    bf16x8 x = *(const bf16x8*)(base + ((q * 128 + j * 16) ^ swz));
#pragma unroll
    for (int e = 0; e < 8; ++e) {
      float f = bf2f(x[e]);
      s += f;
      ss = fmaf(f, f, ss);
    }
  }
  s  += __shfl_xor(s, 1, 64);  ss += __shfl_xor(ss, 1, 64);
  s  += __shfl_xor(s, 2, 64);  ss += __shfl_xor(ss, 2, 64);
  float mu   = s * (1.0f / 256.0f);
  float var  = ss * (1.0f / 256.0f) - mu * mu;
  float rstd = rsqrtf(var + 1e-5f);
  if (q == 0) {
    float* d = (float*)(ST + r * 8);
    d[0] = rstd;
    d[1] = rstd * mu;
  }
}

// q-row staging keeps the precise in-register shuffle stats.
__device__ inline void stage_row_q(const float4 v, int row, char* S, float* STrow, int lane) {
  ushort4 o;
  o.x = f2bf(v.x); o.y = f2bf(v.y); o.z = f2bf(v.z); o.w = f2bf(v.w);
  *(ushort4*)(S + row * 512 + ((lane * 8) ^ ((row & 7) << 4))) = o;
  float s  = v.x + v.y + v.z + v.w;
  float ss = fmaf(v.x, v.x, fmaf(v.y, v.y, fmaf(v.z, v.z, v.w * v.w)));
#pragma unroll
  for (int m = 32; m >= 1; m >>= 1) {
    s  += __shfl_xor(s, m, 64);
    ss += __shfl_xor(ss, m, 64);
  }
  float mu   = s * (1.0f / 256.0f);
  float var  = ss * (1.0f / 256.0f) - mu * mu;
  float rstd = rsqrtf(var + 1e-5f);
  if (lane == 0) { STrow[0] = rstd; STrow[1] = rstd * mu; }
}

// 128x256x256 projection on RAW bf16 rows with LN-fold epilogue; four row-passes of
// 32 rows, acc = 32 regs (R9-proven per-pass pattern). In-place over S.
__device__ inline void proj128_ln(char* S, const char* ST, const short* __restrict__ WB,
                                  const float* __restrict__ u, const float* __restrict__ t,
                                  int wave, int lane) {
#pragma unroll
  for (int p = 0; p < 4; ++p) {
    f32x4 acc[2][4] = {};
#pragma unroll
    for (int ks = 0; ks < 8; ++ks) {
      bf16x8 bb[4];
#pragma unroll
      for (int ntl = 0; ntl < 4; ++ntl)
        bb[ntl] = *(const bf16x8*)(WB + (((wave * 4 + ntl) * 8 + ks) * 64 + lane) * 8);
#pragma unroll
      for (int mt = 0; mt < 2; ++mt) {
        int row = p * 32 + mt * 16 + (lane & 15);
        bf16x8 a = *(const bf16x8*)(S + row * 512 +
                                    ((ks * 64 + (lane >> 4) * 16) ^ ((row & 7) << 4)));
#pragma unroll
        for (int ntl = 0; ntl < 4; ++ntl)
          acc[mt][ntl] = __builtin_amdgcn_mfma_f32_16x16x32_bf16(a, bb[ntl], acc[mt][ntl], 0, 0, 0);
      }
    }
    __syncthreads();   // all waves done reading staged rows p*32..p*32+31
    float2 st[2][4];
#pragma unroll
    for (int mt = 0; mt < 2; ++mt)
#pragma unroll
      for (int reg = 0; reg < 4; ++reg) {
        int r = p * 32 + mt * 16 + (lane >> 4) * 4 + reg;
        st[mt][reg] = *(const float2*)(ST + r * 8);
      }
#pragma unroll
    for (int ntl = 0; ntl < 4; ++ntl) {
      int c = wave * 64 + ntl * 16 + (lane & 15);
      float uc = u[c];
      float tc = t[c];
#pragma unroll
      for (int mt = 0; mt < 2; ++mt)
#pragma unroll
        for (int reg = 0; reg < 4; ++reg) {
          int r = p * 32 + mt * 16 + (lane >> 4) * 4 + reg;
          float val = fmaf(st[mt][reg].x, acc[mt][ntl][reg], fmaf(-st[mt][reg].y, uc, tc));
          *(unsigned short*)(S + r * 512 + ((c * 2) ^ ((r & 7) << 4))) = f2bf(val);
        }
    }
  }
  __syncthreads();     // full projection visible
}

__global__ __launch_bounds__(256, 2) void geo_attn_main(
    const float* __restrict__ query, const float* __restrict__ key_,
    const float* __restrict__ value, const float* __restrict__ bo,
    const short* __restrict__ wsb, const float* __restrict__ utf,
    float* __restrict__ out) {
  __shared__ char smem[78912];
  char* S   = smem;           // [128][512B] swizzled bf16 K/V tile (raw->proj in place)
  char* PR  = smem + 65536;   // [16][64] f32 probs (probs[k][g], g = nl*8+h, nl<8)
  char* QL  = smem + 69632;   // [16][512B]: rows 0-7 q_proj (plain) then OT (swizzled);
                              //             rows 8-15 garbage A-rows for out-proj
  char* ST  = smem + 77824;   // [128] float2 row stats (rstd, rstd*mu)
  char* STQ = smem + 78848;   // [8]  float2 q row stats

  const int tid = threadIdx.x;
  const int lane = tid & 63;
  const int wave = tid >> 6;
  const int blk = blockIdx.x;
  const int b = blk >> 10;            // 1024 blocks per batch
  const int n0 = (blk & 1023) * 8;

  const short* WqB = wsb;
  const short* WkB = wsb + 65536;
  const short* WvB = wsb + 131072;
  const short* WoB = wsb + 196608;
  const float* uq = utf;        const float* tq = utf + 256;
  const float* uk = utf + 512;  const float* tk = utf + 768;
  const float* uv = utf + 1024; const float* tv = utf + 1280;

  const float* ksrc = key_  + (size_t)((b * Nn + n0) * 16) * 256;
  const float* vsrc = value + (size_t)((b * Nn + n0) * 16) * 256;
  const int rbase = wave * 32;        // this wave's 32 staging rows

  // ---- Issue K batch 0 (4 rows); hidden under q-stage + q-proj ----
  float4 kcur[4];
#pragma unroll
  for (int i = 0; i < 4; ++i)
    kcur[i] = *(const float4*)(ksrc + (size_t)(rbase + i) * 256 + lane * 4);

  // ---- Phase 1: q-stage (bf16 + precise stats), two rows per wave (reg-shared) ----
  for (int i = 0; i < 2; ++i) {
    int row = wave * 2 + i;
    float4 v = *(const float4*)(query + (size_t)(b * Nn + n0 + row) * 256 + lane * 4);
    stage_row_q(v, row, S, (float*)(STQ + row * 8), lane);
  }
  __syncthreads();

  // ---- Phase 2: q-proj mini-GEMM (LN-fold epilogue) -> QL rows 0-7 (plain) ----
  {
    f32x4 qacc[4] = {};
#pragma unroll
    for (int ks = 0; ks < 8; ++ks) {
      int arow = lane & 15;
      bf16x8 a = *(const bf16x8*)(S + arow * 512 +
                                  ((ks * 64 + (lane >> 4) * 16) ^ ((arow & 7) << 4)));
#pragma unroll
      for (int ntl = 0; ntl < 4; ++ntl) {
        bf16x8 bb = *(const bf16x8*)(WqB + (((wave * 4 + ntl) * 8 + ks) * 64 + lane) * 8);
        qacc[ntl] = __builtin_amdgcn_mfma_f32_16x16x32_bf16(a, bb, qacc[ntl], 0, 0, 0);
      }
    }
    if ((lane >> 4) < 2) {
#pragma unroll
      for (int ntl = 0; ntl < 4; ++ntl) {
        int c = wave * 64 + ntl * 16 + (lane & 15);
        float uc = uq[c];
        float tc = tq[c];
#pragma unroll
        for (int reg = 0; reg < 4; ++reg) {
          int r = (lane >> 4) * 4 + reg;      // rows 0-7
          float2 stq = *(const float2*)(STQ + r * 8);
          float val = fmaf(stq.x, qacc[ntl][reg], fmaf(-stq.y, uc, tc));
          *(unsigned short*)(QL + r * 512 + c * 2) = f2bf(val);
        }
      }
    }
  }
  __syncthreads();   // QL visible; S free for K-stage

  // ---- Phase 3: K-stage (32 independent cvt-store rows/wave) + stats ----
  {
#pragma unroll
    for (int i = 0; i < 4; ++i) store_row(kcur[i], rbase + i, S, lane);
#pragma unroll
    for (int i = 4; i < 32; ++i) {
      float4 v = *(const float4*)(ksrc + (size_t)(rbase + i) * 256 + lane * 4);
      store_row(v, rbase + i, S, lane);
    }
    wait_lds();
    stats16(S, ST, rbase, lane);
    stats16(S, ST, rbase + 16, lane);
  }
  __syncthreads();

  // ---- Phase 4: K-proj with LN-fold (four row-passes, in-place) ----
  proj128_ln(S, ST, WkB, uk, tk, wave, lane);

  // ---- Issue V batch 0: hidden under logits+softmax ----
  float4 vcur[4];
#pragma unroll
  for (int i = 0; i < 4; ++i)
    vcur[i] = *(const float4*)(vsrc + (size_t)(rbase + i) * 256 + lane * 4);

  // ---- Phase 5: logits + fused softmax (4-lane groups, 4 k/thread) -> PR ----
  {
    int g = tid >> 2;         // 0..63 = nl*8 + h
    int nl = g >> 3, h = g & 7;
    int k0 = (tid & 3) * 4;
    float a[4];
#pragma unroll
    for (int kk = 0; kk < 4; ++kk) {
      int row = nl * 16 + k0 + kk;
      float acc = 0.f;
#pragma unroll
      for (int j4 = 0; j4 < 4; ++j4) {
        bf16x8 qq = *(const bf16x8*)(QL + nl * 512 + h * 64 + j4 * 16);
        bf16x8 kv = *(const bf16x8*)(S + row * 512 +
                                     ((h * 64 + j4 * 16) ^ ((row & 7) << 4)));
#pragma unroll
        for (int j = 0; j < 8; ++j) acc = fmaf(bf2f(qq[j]), bf2f(kv[j]), acc);
      }
      a[kk] = acc * SCALE;
    }
    float m = fmaxf(fmaxf(a[0], a[1]), fmaxf(a[2], a[3]));
#pragma unroll
    for (int msk = 1; msk <= 2; msk <<= 1) m = fmaxf(m, __shfl_xor(m, msk, 64));
    float e[4];
    float ssum = 0.f;
#pragma unroll
    for (int kk = 0; kk < 4; ++kk) { e[kk] = __expf(a[kk] - m); ssum += e[kk]; }
#pragma unroll
    for (int msk = 1; msk <= 2; msk <<= 1) ssum += __shfl_xor(ssum, msk, 64);
    float inv = 1.0f / ssum;
#pragma unroll
    for (int kk = 0; kk < 4; ++kk)
      *(float*)(PR + ((k0 + kk) * 64 + g) * 4) = e[kk] * inv;
  }
  __syncthreads();   // S (K-proj) reads + QL logits-reads done; V-stage may overwrite S

  // ---- Phase 6: V-stage (32 rows/wave) + stats ----
  {
#pragma unroll
    for (int i = 0; i < 4; ++i) store_row(vcur[i], rbase + i, S, lane);
#pragma unroll
    for (int i = 4; i < 32; ++i) {
      float4 v = *(const float4*)(vsrc + (size_t)(rbase + i) * 256 + lane * 4);
      store_row(v, rbase + i, S, lane);
    }
    wait_lds();
    stats16(S, ST, rbase, lane);
    stats16(S, ST, rbase + 16, lane);
  }
  __syncthreads();

  // ---- Phase 7: V-proj with LN-fold (four row-passes, in-place) ----
  proj128_ln(S, ST, WvB, uv, tv, wave, lane);

  // ---- Phase 8: PV, each position written straight into QL (OT tile, swizzled) ----
  // QL's logits-reads finished before the V-stage barrier; no regs held across barriers.
  {
    int c0 = lane * 4;
    int h = c0 >> 5;
    for (int pi = 0; pi < 2; ++pi) {
      int nl = wave * 2 + pi;
      float o0 = 0.f, o1 = 0.f, o2 = 0.f, o3 = 0.f;
#pragma unroll
      for (int k = 0; k < 16; ++k) {
        float p = *(const float*)(PR + (k * 64 + nl * 8 + h) * 4);
        int row = nl * 16 + k;
        ushort4 vv = *(const ushort4*)(S + row * 512 + ((c0 * 2) ^ ((row & 7) << 4)));
        o0 = fmaf(p, bf2f((short)vv.x), o0);
        o1 = fmaf(p, bf2f((short)vv.y), o1);
        o2 = fmaf(p, bf2f((short)vv.z), o2);
        o3 = fmaf(p, bf2f((short)vv.w), o3);
      }
      ushort4 ob;
      ob.x = f2bf(o0); ob.y = f2bf(o1); ob.z = f2bf(o2); ob.w = f2bf(o3);
      *(ushort4*)(QL + nl * 512 + ((c0 * 2) ^ ((nl & 7) << 4))) = ob;
    }
  }
  __syncthreads();   // OT visible (single barrier; S untouched)

  // ---- Phase 9: out-proj GEMM + store (A from QL; rows 8-15 garbage -> discarded) ----
  {
    f32x4 oacc[4] = {};
#pragma unroll
    for (int ks = 0; ks < 8; ++ks) {
      int arow = lane & 15;
      bf16x8 a = *(const bf16x8*)(QL + arow * 512 +
                                  ((ks * 64 + (lane >> 4) * 16) ^ ((arow & 7) << 4)));
#pragma unroll
      for (int ntl = 0; ntl < 4; ++ntl) {
        bf16x8 bb = *(const bf16x8*)(WoB + (((wave * 4 + ntl) * 8 + ks) * 64 + lane) * 8);
        oacc[ntl] = __builtin_amdgcn_mfma_f32_16x16x32_bf16(a, bb, oacc[ntl], 0, 0, 0);
      }
    }
    if ((lane >> 4) < 2) {
#pragma unroll
      for (int ntl = 0; ntl < 4; ++ntl) {
        int c = wave * 64 + ntl * 16 + (lane & 15);
        float bov = bo[c];
#pragma unroll
        for (int reg = 0; reg < 4; ++reg) {
          int r = (lane >> 4) * 4 + reg;    // rows 0-7
          out[(size_t)(b * Nn + n0 + r) * 256 + c] = oacc[ntl][reg] + bov;
        }
      }
    }
  }
}

extern "C" void kernel_launch(void* const* d_in, const int* in_sizes, int n_in,
                              void* d_out, int out_size, void* d_ws, size_t ws_size,
                              hipStream_t stream) {
  const float* query = (const float*)d_in[0];
  const float* key_  = (const float*)d_in[1];
  const float* value = (const float*)d_in[2];
  const float* lnq_g = (const float*)d_in[3];
  const float* lnq_b = (const float*)d_in[4];
  const float* Wq    = (const float*)d_in[5];
  const float* bq    = (const float*)d_in[6];
  const float* lnk_g = (const float*)d_in[7];
  const float* lnk_b = (const float*)d_in[8];
  const float* Wk    = (const float*)d_in[9];
  const float* bk    = (const float*)d_in[10];
  const float* lnv_g = (const float*)d_in[11];
  const float* lnv_b = (const float*)d_in[12];
  const float* Wv    = (const float*)d_in[13];
  const float* bv    = (const float*)d_in[14];
  const float* Wo    = (const float*)d_in[15];
  const float* bo    = (const float*)d_in[16];
  short* wsb = (short*)d_ws;
  float* utf = (float*)((char*)d_ws + 262144 * sizeof(short));
  float* out = (float*)d_out;

  hipLaunchKernelGGL(prep_weights, dim3(256), dim3(256), 0, stream,
                     Wq, Wk, Wv, Wo, lnq_g, lnk_g, lnv_g, wsb);
  hipLaunchKernelGGL(prep_ut, dim3(3, 16), dim3(256), 0, stream,
                     Wq, Wk, Wv, lnq_g, lnq_b, bq, lnk_g, lnk_b, bk,
                     lnv_g, lnv_b, bv, utf);
  hipLaunchKernelGGL(geo_attn_main, dim3(Bb * (Nn / 8)), dim3(256), 0, stream,
                     query, key_, value, bo, wsb, utf, out);
}